// Round 3
// baseline (106.112 us; speedup 1.0000x reference)
//
#include <hip/hip_runtime.h>
#include <math.h>

#define B_ 4
#define C_ 64
#define D_ 32
#define H_ 64
#define W_ 64
#define S_ (D_*H_*W_)      // 131072 spatial per (b,c)
#define S4_ (S_/4)         // 32768

typedef float floatx4 __attribute__((ext_vector_type(4)));

// ---------------- Kernel 1: channel-wise max & mean -> xc[B][2][D][H][W] ----
__global__ __launch_bounds__(256) void reduce_kernel(const float* __restrict__ x,
                                                     float* __restrict__ xc) {
    int i  = blockIdx.x * 256 + threadIdx.x;          // float4 index over B*S/4
    int b  = i >> 15;                                  // i / S4_
    int s4 = i & (S4_ - 1);
    const float4* x4 = reinterpret_cast<const float4*>(x) + (size_t)b * C_ * S4_ + s4;
    float4 v = x4[0];
    float mx0 = v.x, mx1 = v.y, mx2 = v.z, mx3 = v.w;
    float sm0 = v.x, sm1 = v.y, sm2 = v.z, sm3 = v.w;
    #pragma unroll 8
    for (int c = 1; c < C_; ++c) {
        float4 t = x4[(size_t)c * S4_];
        mx0 = fmaxf(mx0, t.x); sm0 += t.x;
        mx1 = fmaxf(mx1, t.y); sm1 += t.y;
        mx2 = fmaxf(mx2, t.z); sm2 += t.z;
        mx3 = fmaxf(mx3, t.w); sm3 += t.w;
    }
    float4* o = reinterpret_cast<float4*>(xc);
    float4 a; a.x = mx0; a.y = mx1; a.z = mx2; a.w = mx3;
    o[((size_t)b * 2 + 0) * S4_ + s4] = a;
    const float inv = 1.0f / 64.0f;
    float4 m; m.x = sm0 * inv; m.y = sm1 * inv; m.z = sm2 * inv; m.w = sm3 * inv;
    o[((size_t)b * 2 + 1) * S4_ + s4] = m;
}

// ---------------- Kernel 2: conv3d(2->1, k7, pad3) + sigmoid -> scale -------
// Tile: 32(W) x 16(H) x 4(D) outputs per 256-thread block, 256 blocks (1/CU).
// Thread: 4 W-outputs x 2 H-outputs. Halo staged one channel at a time:
// 10(z) x 22(y) x 38(x) stored with row stride 40 (16B-aligned b128 reads).
#define HX 40
#define HY 22
#define HZ 10
#define HROW (HY*HX)       // 880: z stride in tile
__global__ __launch_bounds__(256) void conv_kernel(const float* __restrict__ xc,
                                                   const float* __restrict__ cw,
                                                   const float* __restrict__ cb,
                                                   float* __restrict__ scale) {
    __shared__ float tile[HZ * HROW];   // 8800 floats = 34.4 KB
    __shared__ float wl[392];           // one channel's weights, 8-padded rows

    const int tid = threadIdx.x;
    const int b  = blockIdx.z >> 3;
    const int d0 = (blockIdx.z & 7) * 4;
    const int h0 = blockIdx.y * 16;
    const int w0 = blockIdx.x * 32;

    const int wg = tid & 7;            // w-offset = wg*4
    const int hg = (tid >> 3) & 7;     // h-offset = hg*2
    const int dz = tid >> 6;           // 0..3

    float acc[2][4] = {{0.f,0.f,0.f,0.f},{0.f,0.f,0.f,0.f}};

    for (int ch = 0; ch < 2; ++ch) {
        // weights for this channel: wl[kz][ky][8], 8th lane zero
        for (int idx = tid; idx < 392; idx += 256) {
            int kz = idx / 56;
            int r  = idx - kz * 56;
            int ky = r >> 3;
            int kw = r & 7;
            wl[idx] = (kw < 7) ? cw[ch * 343 + kz * 49 + ky * 7 + kw] : 0.f;
        }
        // halo for this channel: logical 10 x 22 x 38
        for (int idx = tid; idx < HZ * HY * 38; idx += 256) {
            int z = idx / (HY * 38);
            int r = idx - z * (HY * 38);
            int y = r / 38;
            int xw = r - y * 38;
            int gd = d0 + z - 3, gh = h0 + y - 3, gw = w0 + xw - 3;
            float v = 0.f;
            if ((unsigned)gd < (unsigned)D_ && (unsigned)gh < (unsigned)H_ &&
                (unsigned)gw < (unsigned)W_)
                v = xc[((size_t)(b * 2 + ch)) * S_ + gd * (H_ * W_) + gh * W_ + gw];
            tile[z * HROW + y * HX + xw] = v;
        }
        __syncthreads();

        for (int kz = 0; kz < 7; ++kz) {
            const float* base = &tile[(dz + kz) * HROW + (hg * 2) * HX + wg * 4];
            float wt_prev[7];
            float wt_cur[7];
            #pragma unroll
            for (int r = 0; r < 8; ++r) {
                float4 f0 = *reinterpret_cast<const float4*>(base + r * HX);
                float4 f1 = *reinterpret_cast<const float4*>(base + r * HX + 4);
                float2 f2 = *reinterpret_cast<const float2*>(base + r * HX + 8);
                float win[10] = {f0.x, f0.y, f0.z, f0.w, f1.x, f1.y, f1.z, f1.w, f2.x, f2.y};
                if (r < 7) {
                    const float* wr = &wl[kz * 56 + r * 8];
                    float4 wa = *reinterpret_cast<const float4*>(wr);
                    float4 wb = *reinterpret_cast<const float4*>(wr + 4);
                    wt_cur[0] = wa.x; wt_cur[1] = wa.y; wt_cur[2] = wa.z; wt_cur[3] = wa.w;
                    wt_cur[4] = wb.x; wt_cur[5] = wb.y; wt_cur[6] = wb.z;
                    // h-output 0 uses ky = r
                    #pragma unroll
                    for (int kw = 0; kw < 7; ++kw) {
                        acc[0][0] = fmaf(win[kw + 0], wt_cur[kw], acc[0][0]);
                        acc[0][1] = fmaf(win[kw + 1], wt_cur[kw], acc[0][1]);
                        acc[0][2] = fmaf(win[kw + 2], wt_cur[kw], acc[0][2]);
                        acc[0][3] = fmaf(win[kw + 3], wt_cur[kw], acc[0][3]);
                    }
                }
                if (r >= 1) {
                    // h-output 1 uses ky = r-1 (weights carried from previous row)
                    #pragma unroll
                    for (int kw = 0; kw < 7; ++kw) {
                        acc[1][0] = fmaf(win[kw + 0], wt_prev[kw], acc[1][0]);
                        acc[1][1] = fmaf(win[kw + 1], wt_prev[kw], acc[1][1]);
                        acc[1][2] = fmaf(win[kw + 2], wt_prev[kw], acc[1][2]);
                        acc[1][3] = fmaf(win[kw + 3], wt_prev[kw], acc[1][3]);
                    }
                }
                if (r < 7) {
                    #pragma unroll
                    for (int k = 0; k < 7; ++k) wt_prev[k] = wt_cur[k];
                }
            }
        }
        __syncthreads();   // before next channel's fill overwrites the tile
    }

    const float bias = cb[0];
    const int d = d0 + dz, h = h0 + hg * 2, w = w0 + wg * 4;
    float* out0 = &scale[(size_t)b * S_ + d * (H_ * W_) + h * W_ + w];
    float4 s0, s1;
    s0.x = 1.0f / (1.0f + __expf(-(acc[0][0] + bias)));
    s0.y = 1.0f / (1.0f + __expf(-(acc[0][1] + bias)));
    s0.z = 1.0f / (1.0f + __expf(-(acc[0][2] + bias)));
    s0.w = 1.0f / (1.0f + __expf(-(acc[0][3] + bias)));
    s1.x = 1.0f / (1.0f + __expf(-(acc[1][0] + bias)));
    s1.y = 1.0f / (1.0f + __expf(-(acc[1][1] + bias)));
    s1.z = 1.0f / (1.0f + __expf(-(acc[1][2] + bias)));
    s1.w = 1.0f / (1.0f + __expf(-(acc[1][3] + bias)));
    *reinterpret_cast<float4*>(out0) = s0;
    *reinterpret_cast<float4*>(out0 + W_) = s1;
}

// ---------------- Kernel 3: out = x * scale (broadcast over C) --------------
#define SCALE_BLOCKS 2048
__global__ __launch_bounds__(256) void scale_kernel(const float* __restrict__ x,
                                                    const float* __restrict__ scale,
                                                    float* __restrict__ out) {
    const size_t total = (size_t)B_ * C_ * S4_;        // 8388608 float4s
    const size_t stride = (size_t)SCALE_BLOCKS * 256;
    for (size_t i = (size_t)blockIdx.x * 256 + threadIdx.x; i < total; i += stride) {
        int b  = (int)(i >> 21);                       // / (C_*S4_)
        int s4 = (int)(i & (S4_ - 1));
        floatx4 xv = reinterpret_cast<const floatx4*>(x)[i];
        floatx4 sv = reinterpret_cast<const floatx4*>(scale)[(size_t)b * S4_ + s4];
        floatx4 o = xv * sv;
        __builtin_nontemporal_store(o, reinterpret_cast<floatx4*>(out) + i);
    }
}

extern "C" void kernel_launch(void* const* d_in, const int* in_sizes, int n_in,
                              void* d_out, int out_size, void* d_ws, size_t ws_size,
                              hipStream_t stream) {
    const float* x  = (const float*)d_in[0];
    const float* cw = (const float*)d_in[1];   // [1][2][7][7][7]
    const float* cb = (const float*)d_in[2];   // [1]
    float* out   = (float*)d_out;
    float* xc    = (float*)d_ws;                       // B*2*S floats (4 MiB)
    float* scale = xc + (size_t)B_ * 2 * S_;           // B*S floats (2 MiB)

    reduce_kernel<<<dim3((B_ * S4_) / 256), dim3(256), 0, stream>>>(x, xc);
    conv_kernel<<<dim3(W_ / 32, H_ / 16, B_ * (D_ / 4)), dim3(256), 0, stream>>>(xc, cw, cb, scale);
    scale_kernel<<<dim3(SCALE_BLOCKS), dim3(256), 0, stream>>>(x, scale, out);
}

// Round 4
// 98.100 us; speedup vs baseline: 1.0817x; 1.0817x over previous
//
#include <hip/hip_runtime.h>
#include <math.h>

#define B_ 4
#define C_ 64
#define D_ 32
#define H_ 64
#define W_ 64
#define S_ (D_*H_*W_)      // 131072 spatial per (b,c)
#define S4_ (S_/4)         // 32768

typedef float floatx4 __attribute__((ext_vector_type(4)));

// ---------------- Kernel 1: channel-wise max & mean -> xc[B][2][D][H][W] ----
__global__ __launch_bounds__(256) void reduce_kernel(const float* __restrict__ x,
                                                     float* __restrict__ xc) {
    int i  = blockIdx.x * 256 + threadIdx.x;          // float4 index over B*S/4
    int b  = i >> 15;                                  // i / S4_
    int s4 = i & (S4_ - 1);
    const float4* x4 = reinterpret_cast<const float4*>(x) + (size_t)b * C_ * S4_ + s4;
    float4 v = x4[0];
    float mx0 = v.x, mx1 = v.y, mx2 = v.z, mx3 = v.w;
    float sm0 = v.x, sm1 = v.y, sm2 = v.z, sm3 = v.w;
    #pragma unroll 8
    for (int c = 1; c < C_; ++c) {
        float4 t = x4[(size_t)c * S4_];
        mx0 = fmaxf(mx0, t.x); sm0 += t.x;
        mx1 = fmaxf(mx1, t.y); sm1 += t.y;
        mx2 = fmaxf(mx2, t.z); sm2 += t.z;
        mx3 = fmaxf(mx3, t.w); sm3 += t.w;
    }
    float4* o = reinterpret_cast<float4*>(xc);
    float4 a; a.x = mx0; a.y = mx1; a.z = mx2; a.w = mx3;
    o[((size_t)b * 2 + 0) * S4_ + s4] = a;
    const float inv = 1.0f / 64.0f;
    float4 m; m.x = sm0 * inv; m.y = sm1 * inv; m.z = sm2 * inv; m.w = sm3 * inv;
    o[((size_t)b * 2 + 1) * S4_ + s4] = m;
}

// ------- Kernel 2 (fused): conv3d(2->1,k7,p3) + sigmoid + out = x*scale -----
// Tile: 32(W) x 16(H) x 4(D) per 256-thread block, 256 blocks (1/CU).
// Thread: 4 W-outputs x 2 H-outputs. Halo one channel at a time:
// 10(z) x 22(y) x 38(x), row stride 40 floats (16B-aligned b128 reads).
// After conv, the block applies its sigmoid tile to all 64 channels of x.
#define HX 40
#define HY 22
#define HZ 10
#define HROW (HY*HX)       // 880: z stride in tile
__global__ __launch_bounds__(256) void conv_gate_kernel(const float* __restrict__ xc,
                                                        const float* __restrict__ x,
                                                        const float* __restrict__ cw,
                                                        const float* __restrict__ cb,
                                                        float* __restrict__ out) {
    __shared__ float tile[HZ * HROW];   // 8800 floats = 35.2 KB
    __shared__ float wl[392];           // one channel's weights, 8-padded rows

    const int tid = threadIdx.x;
    const int b  = blockIdx.z >> 3;
    const int d0 = (blockIdx.z & 7) * 4;
    const int h0 = blockIdx.y * 16;
    const int w0 = blockIdx.x * 32;

    const int wg = tid & 7;            // w-offset = wg*4
    const int hg = (tid >> 3) & 7;     // h-offset = hg*2
    const int dz = tid >> 6;           // 0..3

    float acc[2][4] = {{0.f,0.f,0.f,0.f},{0.f,0.f,0.f,0.f}};

    for (int ch = 0; ch < 2; ++ch) {
        // weights for this channel: wl[kz][ky][8], 8th lane zero
        for (int idx = tid; idx < 392; idx += 256) {
            int kz = idx / 56;
            int r  = idx - kz * 56;
            int ky = r >> 3;
            int kw = r & 7;
            wl[idx] = (kw < 7) ? cw[ch * 343 + kz * 49 + ky * 7 + kw] : 0.f;
        }
        // halo for this channel: logical 10 x 22 x 38 (divisors are
        // compile-time constants -> magic-mul, cheap)
        for (int idx = tid; idx < HZ * HY * 38; idx += 256) {
            int z = idx / (HY * 38);
            int r = idx - z * (HY * 38);
            int y = r / 38;
            int xw = r - y * 38;
            int gd = d0 + z - 3, gh = h0 + y - 3, gw = w0 + xw - 3;
            float v = 0.f;
            if ((unsigned)gd < (unsigned)D_ && (unsigned)gh < (unsigned)H_ &&
                (unsigned)gw < (unsigned)W_)
                v = xc[((size_t)(b * 2 + ch)) * S_ + gd * (H_ * W_) + gh * W_ + gw];
            tile[z * HROW + y * HX + xw] = v;
        }
        __syncthreads();

        for (int kz = 0; kz < 7; ++kz) {
            const float* base = &tile[(dz + kz) * HROW + (hg * 2) * HX + wg * 4];
            float wt_prev[7];
            float wt_cur[7];
            #pragma unroll
            for (int r = 0; r < 8; ++r) {
                float4 f0 = *reinterpret_cast<const float4*>(base + r * HX);
                float4 f1 = *reinterpret_cast<const float4*>(base + r * HX + 4);
                float2 f2 = *reinterpret_cast<const float2*>(base + r * HX + 8);
                float win[10] = {f0.x, f0.y, f0.z, f0.w, f1.x, f1.y, f1.z, f1.w, f2.x, f2.y};
                if (r < 7) {
                    const float* wr = &wl[kz * 56 + r * 8];
                    float4 wa = *reinterpret_cast<const float4*>(wr);
                    float4 wb = *reinterpret_cast<const float4*>(wr + 4);
                    wt_cur[0] = wa.x; wt_cur[1] = wa.y; wt_cur[2] = wa.z; wt_cur[3] = wa.w;
                    wt_cur[4] = wb.x; wt_cur[5] = wb.y; wt_cur[6] = wb.z;
                    #pragma unroll
                    for (int kw = 0; kw < 7; ++kw) {    // h-output 0, ky = r
                        acc[0][0] = fmaf(win[kw + 0], wt_cur[kw], acc[0][0]);
                        acc[0][1] = fmaf(win[kw + 1], wt_cur[kw], acc[0][1]);
                        acc[0][2] = fmaf(win[kw + 2], wt_cur[kw], acc[0][2]);
                        acc[0][3] = fmaf(win[kw + 3], wt_cur[kw], acc[0][3]);
                    }
                }
                if (r >= 1) {
                    #pragma unroll
                    for (int kw = 0; kw < 7; ++kw) {    // h-output 1, ky = r-1
                        acc[1][0] = fmaf(win[kw + 0], wt_prev[kw], acc[1][0]);
                        acc[1][1] = fmaf(win[kw + 1], wt_prev[kw], acc[1][1]);
                        acc[1][2] = fmaf(win[kw + 2], wt_prev[kw], acc[1][2]);
                        acc[1][3] = fmaf(win[kw + 3], wt_prev[kw], acc[1][3]);
                    }
                }
                if (r < 7) {
                    #pragma unroll
                    for (int k = 0; k < 7; ++k) wt_prev[k] = wt_cur[k];
                }
            }
        }
        __syncthreads();   // before next channel's fill overwrites the tile
    }

    // ---- sigmoid in registers ----
    const float bias = cb[0];
    floatx4 s0, s1;
    s0.x = 1.0f / (1.0f + __expf(-(acc[0][0] + bias)));
    s0.y = 1.0f / (1.0f + __expf(-(acc[0][1] + bias)));
    s0.z = 1.0f / (1.0f + __expf(-(acc[0][2] + bias)));
    s0.w = 1.0f / (1.0f + __expf(-(acc[0][3] + bias)));
    s1.x = 1.0f / (1.0f + __expf(-(acc[1][0] + bias)));
    s1.y = 1.0f / (1.0f + __expf(-(acc[1][1] + bias)));
    s1.z = 1.0f / (1.0f + __expf(-(acc[1][2] + bias)));
    s1.w = 1.0f / (1.0f + __expf(-(acc[1][3] + bias)));

    // ---- apply gate to all 64 channels at this thread's 2x4 positions ----
    const int d = d0 + dz, h = h0 + hg * 2, w = w0 + wg * 4;
    const size_t sp = (size_t)d * (H_ * W_) + (size_t)h * W_ + w;
    const float* xp = x + (size_t)b * C_ * S_ + sp;
    float* op = out + (size_t)b * C_ * S_ + sp;
    #pragma unroll 4
    for (int c = 0; c < C_; ++c) {
        const size_t off = (size_t)c * S_;
        floatx4 xv0 = *reinterpret_cast<const floatx4*>(xp + off);
        floatx4 xv1 = *reinterpret_cast<const floatx4*>(xp + off + W_);
        __builtin_nontemporal_store(xv0 * s0, reinterpret_cast<floatx4*>(op + off));
        __builtin_nontemporal_store(xv1 * s1, reinterpret_cast<floatx4*>(op + off + W_));
    }
}

extern "C" void kernel_launch(void* const* d_in, const int* in_sizes, int n_in,
                              void* d_out, int out_size, void* d_ws, size_t ws_size,
                              hipStream_t stream) {
    const float* x  = (const float*)d_in[0];
    const float* cw = (const float*)d_in[1];   // [1][2][7][7][7]
    const float* cb = (const float*)d_in[2];   // [1]
    float* out = (float*)d_out;
    float* xc  = (float*)d_ws;                 // B*2*S floats (4 MiB)

    reduce_kernel<<<dim3((B_ * S4_) / 256), dim3(256), 0, stream>>>(x, xc);
    conv_gate_kernel<<<dim3(W_ / 32, H_ / 16, B_ * (D_ / 4)), dim3(256), 0, stream>>>(
        xc, x, cw, cb, out);
}

// Round 5
// 96.450 us; speedup vs baseline: 1.1002x; 1.0171x over previous
//
#include <hip/hip_runtime.h>
#include <math.h>

#define B_ 4
#define C_ 64
#define D_ 32
#define H_ 64
#define W_ 64
#define S_ (D_*H_*W_)      // 131072 spatial per (b,c)
#define S4_ (S_/4)         // 32768

typedef float floatx4 __attribute__((ext_vector_type(4)));

// ---------------- Kernel 1: channel-wise max & mean -> xc[B][2][D][H][W] ----
__global__ __launch_bounds__(256) void reduce_kernel(const float* __restrict__ x,
                                                     float* __restrict__ xc) {
    int i  = blockIdx.x * 256 + threadIdx.x;          // float4 index over B*S/4
    int b  = i >> 15;                                  // i / S4_
    int s4 = i & (S4_ - 1);
    const float4* x4 = reinterpret_cast<const float4*>(x) + (size_t)b * C_ * S4_ + s4;
    float4 v = x4[0];
    float mx0 = v.x, mx1 = v.y, mx2 = v.z, mx3 = v.w;
    float sm0 = v.x, sm1 = v.y, sm2 = v.z, sm3 = v.w;
    #pragma unroll 8
    for (int c = 1; c < C_; ++c) {
        float4 t = x4[(size_t)c * S4_];
        mx0 = fmaxf(mx0, t.x); sm0 += t.x;
        mx1 = fmaxf(mx1, t.y); sm1 += t.y;
        mx2 = fmaxf(mx2, t.z); sm2 += t.z;
        mx3 = fmaxf(mx3, t.w); sm3 += t.w;
    }
    float4* o = reinterpret_cast<float4*>(xc);
    float4 a; a.x = mx0; a.y = mx1; a.z = mx2; a.w = mx3;
    o[((size_t)b * 2 + 0) * S4_ + s4] = a;
    const float inv = 1.0f / 64.0f;
    float4 m; m.x = sm0 * inv; m.y = sm1 * inv; m.z = sm2 * inv; m.w = sm3 * inv;
    o[((size_t)b * 2 + 1) * S4_ + s4] = m;
}

// ------- Kernel 2 (fused): conv3d(2->1,k7,p3) + sigmoid + out = x*scale -----
// Tile: 32(W) x 8(H) x 4(D) per 256-thread block -> 512 blocks (2/CU, 8 waves).
// Thread: one float4 of W outputs. Halo one channel at a time:
// 10(z) x 14(y) x 38(x), row stride 44 floats (176 B: 16B-aligned AND
// lane bank offsets 12*hg+4*wg mod 32 -> uniform 8 accesses/bank, no excess
// conflict for ds_read_b128).
#define HX 44
#define HY 14
#define HZ 10
#define HROW (HY*HX)       // 616: z stride in tile
__global__ __launch_bounds__(256) void conv_gate_kernel(const float* __restrict__ xc,
                                                        const float* __restrict__ x,
                                                        const float* __restrict__ cw,
                                                        const float* __restrict__ cb,
                                                        float* __restrict__ out) {
    __shared__ float tile[HZ * HROW];   // 6160 floats = 24.6 KB
    __shared__ float wl[392];           // one channel's weights, 8-padded rows

    const int tid = threadIdx.x;
    const int b  = blockIdx.z >> 3;            // 8 d-tiles per batch
    const int d0 = (blockIdx.z & 7) * 4;
    const int h0 = blockIdx.y * 8;
    const int w0 = blockIdx.x * 32;

    const int wg = tid & 7;            // w = w0 + wg*4
    const int hg = (tid >> 3) & 7;     // h = h0 + hg
    const int dz = tid >> 6;           // d = d0 + dz (0..3)

    float acc0 = 0.f, acc1 = 0.f, acc2 = 0.f, acc3 = 0.f;

    for (int ch = 0; ch < 2; ++ch) {
        // weights for this channel: wl[kz][ky][8], 8th lane zero
        for (int idx = tid; idx < 392; idx += 256) {
            int kz = idx / 56;
            int r  = idx - kz * 56;
            int ky = r >> 3;
            int kw = r & 7;
            wl[idx] = (kw < 7) ? cw[ch * 343 + kz * 49 + ky * 7 + kw] : 0.f;
        }
        // halo for this channel: logical 10 x 14 x 38
        for (int idx = tid; idx < HZ * HY * 38; idx += 256) {
            int z = idx / (HY * 38);
            int r = idx - z * (HY * 38);
            int y = r / 38;
            int xw = r - y * 38;
            int gd = d0 + z - 3, gh = h0 + y - 3, gw = w0 + xw - 3;
            float v = 0.f;
            if ((unsigned)gd < (unsigned)D_ && (unsigned)gh < (unsigned)H_ &&
                (unsigned)gw < (unsigned)W_)
                v = xc[((size_t)(b * 2 + ch)) * S_ + gd * (H_ * W_) + gh * W_ + gw];
            tile[z * HROW + y * HX + xw] = v;
        }
        __syncthreads();

        for (int kz = 0; kz < 7; ++kz) {
            const float* base = &tile[(dz + kz) * HROW + hg * HX + wg * 4];
            #pragma unroll
            for (int ky = 0; ky < 7; ++ky) {
                float4 f0 = *reinterpret_cast<const float4*>(base + ky * HX);
                float4 f1 = *reinterpret_cast<const float4*>(base + ky * HX + 4);
                float2 f2 = *reinterpret_cast<const float2*>(base + ky * HX + 8);
                float win[10] = {f0.x, f0.y, f0.z, f0.w, f1.x, f1.y, f1.z, f1.w, f2.x, f2.y};
                const float* wr = &wl[kz * 56 + ky * 8];
                float4 wa = *reinterpret_cast<const float4*>(wr);
                float4 wb = *reinterpret_cast<const float4*>(wr + 4);
                float wt[7] = {wa.x, wa.y, wa.z, wa.w, wb.x, wb.y, wb.z};
                #pragma unroll
                for (int kw = 0; kw < 7; ++kw) {
                    acc0 = fmaf(win[kw + 0], wt[kw], acc0);
                    acc1 = fmaf(win[kw + 1], wt[kw], acc1);
                    acc2 = fmaf(win[kw + 2], wt[kw], acc2);
                    acc3 = fmaf(win[kw + 3], wt[kw], acc3);
                }
            }
        }
        __syncthreads();   // before next channel's fill overwrites the tile
    }

    // ---- sigmoid in registers ----
    const float bias = cb[0];
    floatx4 s0;
    s0.x = 1.0f / (1.0f + __expf(-(acc0 + bias)));
    s0.y = 1.0f / (1.0f + __expf(-(acc1 + bias)));
    s0.z = 1.0f / (1.0f + __expf(-(acc2 + bias)));
    s0.w = 1.0f / (1.0f + __expf(-(acc3 + bias)));

    // ---- apply gate to all 64 channels at this thread's float4 ----
    const int d = d0 + dz, h = h0 + hg, w = w0 + wg * 4;
    const size_t sp = (size_t)d * (H_ * W_) + (size_t)h * W_ + w;
    const float* xp = x + (size_t)b * C_ * S_ + sp;
    float* op = out + (size_t)b * C_ * S_ + sp;
    #pragma unroll 8
    for (int c = 0; c < C_; ++c) {
        const size_t off = (size_t)c * S_;
        floatx4 xv = *reinterpret_cast<const floatx4*>(xp + off);
        __builtin_nontemporal_store(xv * s0, reinterpret_cast<floatx4*>(op + off));
    }
}

extern "C" void kernel_launch(void* const* d_in, const int* in_sizes, int n_in,
                              void* d_out, int out_size, void* d_ws, size_t ws_size,
                              hipStream_t stream) {
    const float* x  = (const float*)d_in[0];
    const float* cw = (const float*)d_in[1];   // [1][2][7][7][7]
    const float* cb = (const float*)d_in[2];   // [1]
    float* out = (float*)d_out;
    float* xc  = (float*)d_ws;                 // B*2*S floats (4 MiB)

    reduce_kernel<<<dim3((B_ * S4_) / 256), dim3(256), 0, stream>>>(x, xc);
    conv_gate_kernel<<<dim3(W_ / 32, H_ / 8, B_ * (D_ / 4)), dim3(256), 0, stream>>>(
        xc, x, cw, cb, out);
}

// Round 6
// 93.539 us; speedup vs baseline: 1.1344x; 1.0311x over previous
//
#include <hip/hip_runtime.h>
#include <math.h>

#define B_ 4
#define C_ 64
#define D_ 32
#define H_ 64
#define W_ 64
#define S_ (D_*H_*W_)      // 131072 spatial per (b,c)
#define S4_ (S_/4)         // 32768

typedef float floatx4 __attribute__((ext_vector_type(4)));

// ---------------- Kernel 1: channel-wise max & mean -> xc[B][2][D][H][W] ----
__global__ __launch_bounds__(256) void reduce_kernel(const float* __restrict__ x,
                                                     float* __restrict__ xc) {
    int i  = blockIdx.x * 256 + threadIdx.x;          // float4 index over B*S/4
    int b  = i >> 15;                                  // i / S4_
    int s4 = i & (S4_ - 1);
    const float4* x4 = reinterpret_cast<const float4*>(x) + (size_t)b * C_ * S4_ + s4;
    float4 v = x4[0];
    float mx0 = v.x, mx1 = v.y, mx2 = v.z, mx3 = v.w;
    float sm0 = v.x, sm1 = v.y, sm2 = v.z, sm3 = v.w;
    #pragma unroll 8
    for (int c = 1; c < C_; ++c) {
        float4 t = x4[(size_t)c * S4_];
        mx0 = fmaxf(mx0, t.x); sm0 += t.x;
        mx1 = fmaxf(mx1, t.y); sm1 += t.y;
        mx2 = fmaxf(mx2, t.z); sm2 += t.z;
        mx3 = fmaxf(mx3, t.w); sm3 += t.w;
    }
    float4* o = reinterpret_cast<float4*>(xc);
    float4 a; a.x = mx0; a.y = mx1; a.z = mx2; a.w = mx3;
    o[((size_t)b * 2 + 0) * S4_ + s4] = a;
    const float inv = 1.0f / 64.0f;
    float4 m; m.x = sm0 * inv; m.y = sm1 * inv; m.z = sm2 * inv; m.w = sm3 * inv;
    o[((size_t)b * 2 + 1) * S4_ + s4] = m;
}

// ------- Kernel 2 (fused): conv3d(2->1,k7,p3) + sigmoid + out = x*scale -----
// Tile: 64(W, full rows) x 4(H) x 4(D) per 256-thread block -> 512 blocks
// (2/CU, 8 waves). Thread: one float4 of W. Gating phase: each wave's 64
// lanes cover 4 adjacent full H-rows -> one CONTIGUOUS 1KB-aligned 1KB span
// per channel per wave (full 256B HBM atoms, L2-merged stores).
// Halo: both channels resident, 2 x 10(z) x 10(y) x 70(x), row stride 72.
#define YS 72
#define ZS (10*YS)         // 720
#define CHS (10*ZS)        // 7200 floats per channel
__global__ __launch_bounds__(256) void conv_gate_kernel(const float* __restrict__ xc,
                                                        const float* __restrict__ x,
                                                        const float* __restrict__ cw,
                                                        const float* __restrict__ cb,
                                                        float* __restrict__ out) {
    __shared__ float tile[2 * CHS];     // 14400 floats = 57.6 KB
    __shared__ float wl[784];           // both channels, 8-padded rows

    const int tid = threadIdx.x;
    const int b  = blockIdx.z >> 3;
    const int d0 = (blockIdx.z & 7) * 4;
    const int h0 = blockIdx.y * 4;

    const int w4 = tid & 15;           // w = 4*w4 (full 64-wide row per 16 lanes)
    const int hh = (tid >> 4) & 3;     // h = h0 + hh
    const int dd = tid >> 6;           // d = d0 + dd

    // weights, both channels: wl[ch][kz][ky][8], 8th lane zero
    for (int idx = tid; idx < 784; idx += 256) {
        int ch = idx / 392;
        int r  = idx - ch * 392;
        int kz = r / 56;
        int r2 = r - kz * 56;
        int ky = r2 >> 3;
        int kw = r2 & 7;
        wl[idx] = (kw < 7) ? cw[ch * 343 + kz * 49 + ky * 7 + kw] : 0.f;
    }
    // halo, both channels: logical 2 x 10 x 10 x 70
    for (int idx = tid; idx < 2 * 10 * 10 * 70; idx += 256) {
        int ch = idx / 7000;
        int r  = idx - ch * 7000;
        int z  = r / 700;
        int r2 = r - z * 700;
        int y  = r2 / 70;
        int xw = r2 - y * 70;
        int gd = d0 + z - 3, gh = h0 + y - 3, gw = xw - 3;
        float v = 0.f;
        if ((unsigned)gd < (unsigned)D_ && (unsigned)gh < (unsigned)H_ &&
            (unsigned)gw < (unsigned)W_)
            v = xc[((size_t)(b * 2 + ch)) * S_ + gd * (H_ * W_) + gh * W_ + gw];
        tile[ch * CHS + z * ZS + y * YS + xw] = v;
    }
    __syncthreads();

    float acc0 = 0.f, acc1 = 0.f, acc2 = 0.f, acc3 = 0.f;
    for (int ch = 0; ch < 2; ++ch) {
        for (int kz = 0; kz < 7; ++kz) {
            const float* base = &tile[ch * CHS + (dd + kz) * ZS + hh * YS + w4 * 4];
            #pragma unroll
            for (int ky = 0; ky < 7; ++ky) {
                float4 f0 = *reinterpret_cast<const float4*>(base + ky * YS);
                float4 f1 = *reinterpret_cast<const float4*>(base + ky * YS + 4);
                float2 f2 = *reinterpret_cast<const float2*>(base + ky * YS + 8);
                float win[10] = {f0.x, f0.y, f0.z, f0.w, f1.x, f1.y, f1.z, f1.w, f2.x, f2.y};
                const float* wr = &wl[ch * 392 + kz * 56 + ky * 8];
                float4 wa = *reinterpret_cast<const float4*>(wr);
                float4 wb = *reinterpret_cast<const float4*>(wr + 4);
                float wt[7] = {wa.x, wa.y, wa.z, wa.w, wb.x, wb.y, wb.z};
                #pragma unroll
                for (int kw = 0; kw < 7; ++kw) {
                    acc0 = fmaf(win[kw + 0], wt[kw], acc0);
                    acc1 = fmaf(win[kw + 1], wt[kw], acc1);
                    acc2 = fmaf(win[kw + 2], wt[kw], acc2);
                    acc3 = fmaf(win[kw + 3], wt[kw], acc3);
                }
            }
        }
    }

    // ---- sigmoid in registers ----
    const float bias = cb[0];
    floatx4 s0;
    s0.x = 1.0f / (1.0f + __expf(-(acc0 + bias)));
    s0.y = 1.0f / (1.0f + __expf(-(acc1 + bias)));
    s0.z = 1.0f / (1.0f + __expf(-(acc2 + bias)));
    s0.w = 1.0f / (1.0f + __expf(-(acc3 + bias)));

    // ---- apply gate to all 64 channels at this thread's float4 ----
    const int d = d0 + dd, h = h0 + hh, w = w4 * 4;
    const size_t sp = (size_t)d * (H_ * W_) + (size_t)h * W_ + w;
    const float* xp = x + (size_t)b * C_ * S_ + sp;
    float* op = out + (size_t)b * C_ * S_ + sp;
    #pragma unroll 8
    for (int c = 0; c < C_; ++c) {
        const size_t off = (size_t)c * S_;
        floatx4 xv = *reinterpret_cast<const floatx4*>(xp + off);
        *reinterpret_cast<floatx4*>(op + off) = xv * s0;
    }
}

extern "C" void kernel_launch(void* const* d_in, const int* in_sizes, int n_in,
                              void* d_out, int out_size, void* d_ws, size_t ws_size,
                              hipStream_t stream) {
    const float* x  = (const float*)d_in[0];
    const float* cw = (const float*)d_in[1];   // [1][2][7][7][7]
    const float* cb = (const float*)d_in[2];   // [1]
    float* out = (float*)d_out;
    float* xc  = (float*)d_ws;                 // B*2*S floats (4 MiB)

    reduce_kernel<<<dim3((B_ * S4_) / 256), dim3(256), 0, stream>>>(x, xc);
    conv_gate_kernel<<<dim3(1, H_ / 4, B_ * (D_ / 4)), dim3(256), 0, stream>>>(
        xc, x, cw, cb, out);
}